// Round 4
// baseline (112.218 us; speedup 1.0000x reference)
//
#include <hip/hip_runtime.h>

// lhs: [8, 1023, 768] f32, rhs: [8, 8192, 768] f32
// N = 1024, F = 8, EXP = 1
// out[b,n,m] = cos_sim(lhs[b,n], rhs[b,m]) if (m % 1024) == n+1 else -1e9
constexpr int B    = 8;
constexpr int N1   = 1023;
constexpr int NBLK = 1024;
constexpr int D    = 768;
constexpr int F    = 8;
constexpr int NTOT = 8192;
constexpr float NEG = -1e9f;

typedef float v4f __attribute__((ext_vector_type(4)));

// ---------- kernel 1: pure write stream, NEG everywhere ----------
__global__ __launch_bounds__(256)
void fill_kernel(float* __restrict__ out) {
    constexpr size_t TOT4 = (size_t)B * N1 * NTOT / 4;   // 16,760,832 float4
    v4f neg4 = {NEG, NEG, NEG, NEG};
    v4f* o4 = (v4f*)out;
    size_t stride = (size_t)gridDim.x * blockDim.x;
    for (size_t i = (size_t)blockIdx.x * blockDim.x + threadIdx.x;
         i < TOT4; i += stride) {
        __builtin_nontemporal_store(neg4, &o4[i]);
    }
}

// ---------- kernel 2: pure read stream + 1 dword store per wave ----------
__global__ __launch_bounds__(256)
void dot_kernel(const float* __restrict__ lhs,
                const float* __restrict__ rhs,
                float* __restrict__ out) {
    int t    = threadIdx.x;
    int wave = t >> 6;
    int lane = t & 63;
    int gi   = blockIdx.x * 4 + wave;        // [0, 65472)

    // n fastest-varying -> consecutive waves read consecutive rhs rows
    int n   = gi % N1;
    int tmp = gi / N1;
    int f   = tmp % F;
    int b   = tmp / F;

    const v4f* l4 = (const v4f*)(lhs + ((size_t)b * N1 + n) * D);
    const v4f* r4 = (const v4f*)(rhs + ((size_t)b * NTOT + (size_t)f * NBLK + (n + 1)) * D);

    // 192 float4 per row, 3 per lane. rhs is read-once -> nt loads; lhs cached (8x reuse).
    v4f a0 = l4[lane];
    v4f a1 = l4[lane + 64];
    v4f a2 = l4[lane + 128];
    v4f c0 = __builtin_nontemporal_load(&r4[lane]);
    v4f c1 = __builtin_nontemporal_load(&r4[lane + 64]);
    v4f c2 = __builtin_nontemporal_load(&r4[lane + 128]);

    float dot = a0.x*c0.x + a0.y*c0.y + a0.z*c0.z + a0.w*c0.w
              + a1.x*c1.x + a1.y*c1.y + a1.z*c1.z + a1.w*c1.w
              + a2.x*c2.x + a2.y*c2.y + a2.z*c2.z + a2.w*c2.w;
    float l2  = a0.x*a0.x + a0.y*a0.y + a0.z*a0.z + a0.w*a0.w
              + a1.x*a1.x + a1.y*a1.y + a1.z*a1.z + a1.w*a1.w
              + a2.x*a2.x + a2.y*a2.y + a2.z*a2.z + a2.w*a2.w;
    float r2  = c0.x*c0.x + c0.y*c0.y + c0.z*c0.z + c0.w*c0.w
              + c1.x*c1.x + c1.y*c1.y + c1.z*c1.z + c1.w*c1.w
              + c2.x*c2.x + c2.y*c2.y + c2.z*c2.z + c2.w*c2.w;

    // 64-lane butterfly reduce
    #pragma unroll
    for (int off = 32; off >= 1; off >>= 1) {
        dot += __shfl_xor(dot, off, 64);
        l2  += __shfl_xor(l2,  off, 64);
        r2  += __shfl_xor(r2,  off, 64);
    }
    float sim = dot * rsqrtf(l2 * r2);       // EXP == 1

    if (lane == 0) {
        // single dword over the pre-filled NEG background
        out[((size_t)b * N1 + n) * NTOT + (size_t)f * NBLK + (n + 1)] = sim;
    }
}

extern "C" void kernel_launch(void* const* d_in, const int* in_sizes, int n_in,
                              void* d_out, int out_size, void* d_ws, size_t ws_size,
                              hipStream_t stream) {
    const float* lhs = (const float*)d_in[0];
    const float* rhs = (const float*)d_in[1];
    float* out = (float*)d_out;

    fill_kernel<<<4096, 256, 0, stream>>>(out);
    dot_kernel<<<(B * N1 * F) / 4, 256, 0, stream>>>(lhs, rhs, out);
}

// Round 5
// 96.906 us; speedup vs baseline: 1.1580x; 1.1580x over previous
//
#include <hip/hip_runtime.h>

// lhs: [8, 1023, 768] f32, rhs: [8, 8192, 768] f32
// N = 1024, F = 8, EXP = 1
// out[b,n,m] = cos_sim(lhs[b,n], rhs[b,m]) if (m % 1024) == n+1 else -1e9
constexpr int B    = 8;
constexpr int N1   = 1023;
constexpr int NBLK = 1024;
constexpr int D    = 768;
constexpr int F    = 8;
constexpr int NTOT = 8192;
constexpr float NEG = -1e9f;

typedef float v4f __attribute__((ext_vector_type(4)));

__global__ __launch_bounds__(256)
void lcs_kernel(const float* __restrict__ lhs,
                const float* __restrict__ rhs,
                float* __restrict__ out) {
    // one WAVE per (b, n): fills the whole out[b,n,:] row (8 segments) and
    // computes all 8 kept similarities. 4 independent waves/block, no LDS.
    int t    = threadIdx.x;
    int wave = t >> 6;
    int lane = t & 63;
    int gi   = blockIdx.x * 4 + wave;        // [0, 8184)

    int n = gi % N1;
    int b = gi / N1;

    const v4f* l4 = (const v4f*)(lhs + ((size_t)b * N1 + n) * D);
    v4f*       o4 = (v4f*)(out + ((size_t)b * N1 + n) * NTOT);

    int keep_col   = n + 1;                  // same offset within every segment
    int q_seg      = keep_col >> 2;          // owner quad within a 256-quad segment
    int owner_lane = q_seg & 63;
    int owner_sub  = q_seg >> 6;             // 0..3
    int r          = keep_col & 3;

    // 1) fire-and-forget NEG fill of the full 32 KB row (2048 quads, 32/lane);
    //    owner quads (one per segment) are skipped and written later with sim.
    v4f neg4 = {NEG, NEG, NEG, NEG};
    #pragma unroll
    for (int it = 0; it < 32; ++it) {
        if (!(lane == owner_lane && (it & 3) == owner_sub)) {
            __builtin_nontemporal_store(neg4, &o4[it * 64 + lane]);
        }
    }

    // 2) all loads issued up front: 3 lhs + 24 rhs quads per lane, all
    //    read-once -> nontemporal. 432 B/lane in flight.
    v4f a0 = __builtin_nontemporal_load(l4 + lane);
    v4f a1 = __builtin_nontemporal_load(l4 + lane + 64);
    v4f a2 = __builtin_nontemporal_load(l4 + lane + 128);

    const v4f* rbase = (const v4f*)rhs + ((size_t)b * NTOT + keep_col) * (D / 4);
    constexpr size_t FSTR = (size_t)NBLK * (D / 4);   // quads between f-rows

    v4f c0[F], c1[F], c2[F];
    #pragma unroll
    for (int f = 0; f < F; ++f) {
        const v4f* rf = rbase + (size_t)f * FSTR;
        c0[f] = __builtin_nontemporal_load(rf + lane);
        c1[f] = __builtin_nontemporal_load(rf + lane + 64);
        c2[f] = __builtin_nontemporal_load(rf + lane + 128);
    }

    // 3) lhs norm (once per row)
    float l2 = a0.x*a0.x + a0.y*a0.y + a0.z*a0.z + a0.w*a0.w
             + a1.x*a1.x + a1.y*a1.y + a1.z*a1.z + a1.w*a1.w
             + a2.x*a2.x + a2.y*a2.y + a2.z*a2.z + a2.w*a2.w;
    #pragma unroll
    for (int off = 32; off >= 1; off >>= 1) l2 += __shfl_xor(l2, off, 64);

    // 4) per-f dot + rhs norm, reduce, owner writes its quad with sim patched
    #pragma unroll
    for (int f = 0; f < F; ++f) {
        float dot = a0.x*c0[f].x + a0.y*c0[f].y + a0.z*c0[f].z + a0.w*c0[f].w
                  + a1.x*c1[f].x + a1.y*c1[f].y + a1.z*c1[f].z + a1.w*c1[f].w
                  + a2.x*c2[f].x + a2.y*c2[f].y + a2.z*c2[f].z + a2.w*c2[f].w;
        float r2  = c0[f].x*c0[f].x + c0[f].y*c0[f].y + c0[f].z*c0[f].z + c0[f].w*c0[f].w
                  + c1[f].x*c1[f].x + c1[f].y*c1[f].y + c1[f].z*c1[f].z + c1[f].w*c1[f].w
                  + c2[f].x*c2[f].x + c2[f].y*c2[f].y + c2[f].z*c2[f].z + c2[f].w*c2[f].w;
        #pragma unroll
        for (int off = 32; off >= 1; off >>= 1) {
            dot += __shfl_xor(dot, off, 64);
            r2  += __shfl_xor(r2,  off, 64);
        }
        float sim = dot * rsqrtf(l2 * r2);   // EXP == 1

        if (lane == owner_lane) {
            v4f v = neg4;
            v[r] = sim;
            __builtin_nontemporal_store(v, &o4[f * 256 + q_seg]);
        }
    }
}

extern "C" void kernel_launch(void* const* d_in, const int* in_sizes, int n_in,
                              void* d_out, int out_size, void* d_ws, size_t ws_size,
                              hipStream_t stream) {
    const float* lhs = (const float*)d_in[0];
    const float* rhs = (const float*)d_in[1];
    float* out = (float*)d_out;

    int grid = (B * N1) / 4;   // 2046 blocks, one row per wave
    lcs_kernel<<<grid, 256, 0, stream>>>(lhs, rhs, out);
}

// Round 6
// 86.067 us; speedup vs baseline: 1.3039x; 1.1259x over previous
//
#include <hip/hip_runtime.h>

// lhs: [8, 1023, 768] f32, rhs: [8, 8192, 768] f32
// N = 1024, F = 8, EXP = 1
// out[b,n,m] = cos_sim(lhs[b,n], rhs[b,m]) if (m % 1024) == n+1 else -1e9
constexpr int B    = 8;
constexpr int N1   = 1023;
constexpr int NBLK = 1024;
constexpr int D    = 768;
constexpr int F    = 8;
constexpr int NTOT = 8192;
constexpr float NEG = -1e9f;

typedef float v4f __attribute__((ext_vector_type(4)));

// Heterogeneous launch: 18414 blocks of 256 threads.
//   blockIdx % 9 == 0  -> FILL block  (2046 blocks, 4 waves each = 8184 waves,
//                          one wave per output row; pure nt-store stream)
//   otherwise          -> DOT block   (16368 blocks, 4 waves each = 65472 waves,
//                          one wave per (b,n,f); pure read stream + 1 quad store)
// Fill waves skip the 8 "owner" quads of their row; dot waves write exactly
// those quads (sim patched in). Disjoint addresses -> no race, deterministic.
__global__ __launch_bounds__(256)
void lcs_kernel(const float* __restrict__ lhs,
                const float* __restrict__ rhs,
                float* __restrict__ out) {
    int t    = threadIdx.x;
    int wave = t >> 6;
    int lane = t & 63;

    int bid = blockIdx.x;
    int g   = bid / 9;
    int p   = bid - g * 9;

    v4f neg4 = {NEG, NEG, NEG, NEG};

    if (p == 0) {
        // ---------------- FILL wave: one output row (2048 quads = 32 KB) ----
        int row = g * 4 + wave;              // [0, 8184)
        int n   = row % N1;
        int own = (n + 1) >> 2;              // owner quad index within each segment
        int owner_lane = own & 63;
        int owner_sub  = own >> 6;           // 0..3

        v4f* o4 = (v4f*)out + (size_t)row * (NTOT / 4);
        #pragma unroll
        for (int it = 0; it < 32; ++it) {
            if (!(lane == owner_lane && (it & 3) == owner_sub)) {
                __builtin_nontemporal_store(neg4, &o4[it * 64 + lane]);
            }
        }
    } else {
        // ---------------- DOT wave: one (b, n, f) --------------------------
        int dot_id = g * 8 + (p - 1);        // [0, 16368)
        int gi     = dot_id * 4 + wave;      // [0, 65472)

        // n fastest-varying -> consecutive waves read consecutive rhs rows
        int n   = gi % N1;
        int tmp = gi / N1;
        int f   = tmp % F;
        int b   = tmp / F;

        const v4f* l4 = (const v4f*)(lhs + ((size_t)b * N1 + n) * D);
        const v4f* r4 = (const v4f*)(rhs + ((size_t)b * NTOT + (size_t)f * NBLK + (n + 1)) * D);

        // loads only (no fill duty): 3 lhs (cached, 8x reuse) + 3 rhs (nt)
        v4f a0 = l4[lane];
        v4f a1 = l4[lane + 64];
        v4f a2 = l4[lane + 128];
        v4f c0 = __builtin_nontemporal_load(&r4[lane]);
        v4f c1 = __builtin_nontemporal_load(&r4[lane + 64]);
        v4f c2 = __builtin_nontemporal_load(&r4[lane + 128]);

        float dot = a0.x*c0.x + a0.y*c0.y + a0.z*c0.z + a0.w*c0.w
                  + a1.x*c1.x + a1.y*c1.y + a1.z*c1.z + a1.w*c1.w
                  + a2.x*c2.x + a2.y*c2.y + a2.z*c2.z + a2.w*c2.w;
        float l2  = a0.x*a0.x + a0.y*a0.y + a0.z*a0.z + a0.w*a0.w
                  + a1.x*a1.x + a1.y*a1.y + a1.z*a1.z + a1.w*a1.w
                  + a2.x*a2.x + a2.y*a2.y + a2.z*a2.z + a2.w*a2.w;
        float r2  = c0.x*c0.x + c0.y*c0.y + c0.z*c0.z + c0.w*c0.w
                  + c1.x*c1.x + c1.y*c1.y + c1.z*c1.z + c1.w*c1.w
                  + c2.x*c2.x + c2.y*c2.y + c2.z*c2.z + c2.w*c2.w;

        #pragma unroll
        for (int off = 32; off >= 1; off >>= 1) {
            dot += __shfl_xor(dot, off, 64);
            l2  += __shfl_xor(l2,  off, 64);
            r2  += __shfl_xor(r2,  off, 64);
        }
        float sim = dot * rsqrtf(l2 * r2);   // EXP == 1

        int keep_col   = n + 1;
        int q_seg      = keep_col >> 2;
        if (lane == (q_seg & 63)) {
            int r = keep_col & 3;
            v4f v = neg4;
            v[r] = sim;
            v4f* o4 = (v4f*)(out + ((size_t)b * N1 + n) * NTOT + (size_t)f * NBLK);
            __builtin_nontemporal_store(v, &o4[q_seg]);
        }
    }
}

extern "C" void kernel_launch(void* const* d_in, const int* in_sizes, int n_in,
                              void* d_out, int out_size, void* d_ws, size_t ws_size,
                              hipStream_t stream) {
    const float* lhs = (const float*)d_in[0];
    const float* rhs = (const float*)d_in[1];
    float* out = (float*)d_out;

    int grid = 18414;   // 2046 fill blocks + 16368 dot blocks, interleaved 1:8
    lcs_kernel<<<grid, 256, 0, stream>>>(lhs, rhs, out);
}

// Round 7
// 84.241 us; speedup vs baseline: 1.3321x; 1.0217x over previous
//
#include <hip/hip_runtime.h>

// lhs: [8, 1023, 768] f32, rhs: [8, 8192, 768] f32
// N = 1024, F = 8, EXP = 1
// out[b,n,m] = cos_sim(lhs[b,n], rhs[b,m]) if (m % 1024) == n+1 else -1e9
constexpr int B    = 8;
constexpr int N1   = 1023;
constexpr int NBLK = 1024;
constexpr int D    = 768;
constexpr int F    = 8;
constexpr int NTOT = 8192;
constexpr float NEG = -1e9f;

typedef float v4f __attribute__((ext_vector_type(4)));

// Heterogeneous launch, 18414 blocks of 256 threads:
//   blockIdx % 9 == 0 -> FILL block (8184 waves, one output row each;
//                        pure nt-store stream, skips the owner 128B line/segment)
//   otherwise         -> DOT block  (65472 waves, one (b,n,f) each;
//                        pure read stream + ONE full 128B line store)
// Ownership is 128B-line aligned: every line of `out` is written by exactly
// one wave, full-line -> no split-line masked writebacks across XCDs.
__global__ __launch_bounds__(256)
void lcs_kernel(const float* __restrict__ lhs,
                const float* __restrict__ rhs,
                float* __restrict__ out) {
    int t    = threadIdx.x;
    int wave = t >> 6;
    int lane = t & 63;

    int bid = blockIdx.x;
    int g   = bid / 9;
    int p   = bid - g * 9;

    v4f neg4 = {NEG, NEG, NEG, NEG};

    if (p == 0) {
        // ---------------- FILL wave: one output row (2048 quads = 32 KB) ----
        int row = g * 4 + wave;              // [0, 8184)
        int n   = row % N1;
        int ol  = ((n + 1) >> 2) >> 3;       // owner 128B line within each segment [0,32)

        v4f* o4 = (v4f*)out + (size_t)row * (NTOT / 4);
        #pragma unroll
        for (int it = 0; it < 32; ++it) {
            // quad idx = it*64 + lane; its line-within-segment = (it*8 + lane/8) & 31
            if (((it * 8 + (lane >> 3)) & 31) != ol) {
                __builtin_nontemporal_store(neg4, &o4[it * 64 + lane]);
            }
        }
    } else {
        // ---------------- DOT wave: one (b, n, f) --------------------------
        int dot_id = g * 8 + (p - 1);        // [0, 16368)
        int gi     = dot_id * 4 + wave;      // [0, 65472)

        // n fastest-varying -> consecutive waves read consecutive rhs rows
        int n   = gi % N1;
        int tmp = gi / N1;
        int f   = tmp % F;
        int b   = tmp / F;

        const v4f* l4 = (const v4f*)(lhs + ((size_t)b * N1 + n) * D);
        const v4f* r4 = (const v4f*)(rhs + ((size_t)b * NTOT + (size_t)f * NBLK + (n + 1)) * D);

        // 3 lhs quads (cached, 8x reuse) + 3 rhs quads (read-once, nt)
        v4f a0 = l4[lane];
        v4f a1 = l4[lane + 64];
        v4f a2 = l4[lane + 128];
        v4f c0 = __builtin_nontemporal_load(&r4[lane]);
        v4f c1 = __builtin_nontemporal_load(&r4[lane + 64]);
        v4f c2 = __builtin_nontemporal_load(&r4[lane + 128]);

        float dot = a0.x*c0.x + a0.y*c0.y + a0.z*c0.z + a0.w*c0.w
                  + a1.x*c1.x + a1.y*c1.y + a1.z*c1.z + a1.w*c1.w
                  + a2.x*c2.x + a2.y*c2.y + a2.z*c2.z + a2.w*c2.w;
        float l2  = a0.x*a0.x + a0.y*a0.y + a0.z*a0.z + a0.w*a0.w
                  + a1.x*a1.x + a1.y*a1.y + a1.z*a1.z + a1.w*a1.w
                  + a2.x*a2.x + a2.y*a2.y + a2.z*a2.z + a2.w*a2.w;
        float r2  = c0.x*c0.x + c0.y*c0.y + c0.z*c0.z + c0.w*c0.w
                  + c1.x*c1.x + c1.y*c1.y + c1.z*c1.z + c1.w*c1.w
                  + c2.x*c2.x + c2.y*c2.y + c2.z*c2.z + c2.w*c2.w;

        #pragma unroll
        for (int off = 32; off >= 1; off >>= 1) {
            dot += __shfl_xor(dot, off, 64);
            l2  += __shfl_xor(l2,  off, 64);
            r2  += __shfl_xor(r2,  off, 64);
        }
        float sim = dot * rsqrtf(l2 * r2);   // EXP == 1

        // write the full 128B owner line (8 quads), sim patched at keep_col
        int keep_col = n + 1;
        int q_seg    = keep_col >> 2;        // owner quad within segment [0,256)
        int own_base = q_seg & ~7;           // 128B-aligned line start (quad units)
        if (lane < 8) {
            int qidx = own_base + lane;
            v4f v = neg4;
            if (qidx == q_seg) v[keep_col & 3] = sim;
            v4f* o4 = (v4f*)(out + ((size_t)b * N1 + n) * NTOT + (size_t)f * NBLK);
            __builtin_nontemporal_store(v, &o4[qidx]);
        }
    }
}

extern "C" void kernel_launch(void* const* d_in, const int* in_sizes, int n_in,
                              void* d_out, int out_size, void* d_ws, size_t ws_size,
                              hipStream_t stream) {
    const float* lhs = (const float*)d_in[0];
    const float* rhs = (const float*)d_in[1];
    float* out = (float*)d_out;

    int grid = 18414;   // 2046 fill blocks + 16368 dot blocks, interleaved 1:8
    lcs_kernel<<<grid, 256, 0, stream>>>(lhs, rhs, out);
}

// Round 8
// 83.986 us; speedup vs baseline: 1.3361x; 1.0030x over previous
//
#include <hip/hip_runtime.h>

// lhs: [8, 1023, 768] f32, rhs: [8, 8192, 768] f32
// N = 1024, F = 8, EXP = 1
// out[b,n,m] = cos_sim(lhs[b,n], rhs[b,m]) if (m % 1024) == n+1 else -1e9
constexpr int B    = 8;
constexpr int N1   = 1023;
constexpr int NBLK = 1024;
constexpr int D    = 768;
constexpr int F    = 8;
constexpr int NTOT = 8192;
constexpr float NEG = -1e9f;

typedef float v4f __attribute__((ext_vector_type(4)));

// Heterogeneous launch, 6138 blocks of 256 threads, interleaved 1 fill : 2 dot.
//   FILL block (p==0): 4 waves, one output row each (pure nt-store stream,
//                      skips the owner 128B line in each 1024-segment).
//   DOT block  (p>0):  4 waves, each handles (b, n, h) = 4 dots f=h*4..h*4+3
//                      sharing one lhs row; 15 loads in flight, then 4
//                      reduce+full-line stores. Disjoint addresses vs fill.
__global__ __launch_bounds__(256)
void lcs_kernel(const float* __restrict__ lhs,
                const float* __restrict__ rhs,
                float* __restrict__ out) {
    int t    = threadIdx.x;
    int wave = t >> 6;
    int lane = t & 63;

    int bid = blockIdx.x;
    int g   = bid / 3;
    int p   = bid - g * 3;

    v4f neg4 = {NEG, NEG, NEG, NEG};

    if (p == 0) {
        // ---------------- FILL wave: one output row (2048 quads = 32 KB) ----
        int row = g * 4 + wave;              // [0, 8184)
        int n   = row % N1;
        int ol  = ((n + 1) >> 2) >> 3;       // owner 128B line within each segment

        v4f* o4 = (v4f*)out + (size_t)row * (NTOT / 4);
        #pragma unroll
        for (int it = 0; it < 32; ++it) {
            if (((it * 8 + (lane >> 3)) & 31) != ol) {
                __builtin_nontemporal_store(neg4, &o4[it * 64 + lane]);
            }
        }
    } else {
        // ---------------- DOT wave: (b, n, h) -> 4 dots ---------------------
        int gi  = (g * 2 + (p - 1)) * 4 + wave;   // [0, 16368)
        int n   = gi % N1;                        // n fastest -> sequential rhs
        int tmp = gi / N1;
        int h   = tmp & 1;
        int b   = tmp >> 1;

        const v4f* l4 = (const v4f*)(lhs + ((size_t)b * N1 + n) * D);
        v4f a0 = l4[lane];
        v4f a1 = l4[lane + 64];
        v4f a2 = l4[lane + 128];

        const v4f* rbase = (const v4f*)rhs
            + ((size_t)b * NTOT + (size_t)h * 4 * NBLK + (n + 1)) * (D / 4);
        constexpr size_t FSTR = (size_t)NBLK * (D / 4);   // quads between f-rows

        v4f c0[4], c1[4], c2[4];
        #pragma unroll
        for (int ff = 0; ff < 4; ++ff) {
            const v4f* rf = rbase + (size_t)ff * FSTR;
            c0[ff] = __builtin_nontemporal_load(rf + lane);
            c1[ff] = __builtin_nontemporal_load(rf + lane + 64);
            c2[ff] = __builtin_nontemporal_load(rf + lane + 128);
        }

        // lhs norm once
        float l2 = a0.x*a0.x + a0.y*a0.y + a0.z*a0.z + a0.w*a0.w
                 + a1.x*a1.x + a1.y*a1.y + a1.z*a1.z + a1.w*a1.w
                 + a2.x*a2.x + a2.y*a2.y + a2.z*a2.z + a2.w*a2.w;
        #pragma unroll
        for (int off = 32; off >= 1; off >>= 1) l2 += __shfl_xor(l2, off, 64);

        int keep_col = n + 1;
        int q_seg    = keep_col >> 2;
        int own_base = q_seg & ~7;           // 128B-aligned owner line (quads)
        int r        = keep_col & 3;
        v4f* orow = (v4f*)(out + ((size_t)b * N1 + n) * NTOT);

        #pragma unroll
        for (int ff = 0; ff < 4; ++ff) {
            float dt = a0.x*c0[ff].x + a0.y*c0[ff].y + a0.z*c0[ff].z + a0.w*c0[ff].w
                     + a1.x*c1[ff].x + a1.y*c1[ff].y + a1.z*c1[ff].z + a1.w*c1[ff].w
                     + a2.x*c2[ff].x + a2.y*c2[ff].y + a2.z*c2[ff].z + a2.w*c2[ff].w;
            float r2 = c0[ff].x*c0[ff].x + c0[ff].y*c0[ff].y + c0[ff].z*c0[ff].z + c0[ff].w*c0[ff].w
                     + c1[ff].x*c1[ff].x + c1[ff].y*c1[ff].y + c1[ff].z*c1[ff].z + c1[ff].w*c1[ff].w
                     + c2[ff].x*c2[ff].x + c2[ff].y*c2[ff].y + c2[ff].z*c2[ff].z + c2[ff].w*c2[ff].w;
            #pragma unroll
            for (int off = 32; off >= 1; off >>= 1) {
                dt += __shfl_xor(dt, off, 64);
                r2 += __shfl_xor(r2, off, 64);
            }
            float sim = dt * rsqrtf(l2 * r2);   // EXP == 1

            // full 128B owner line for segment f = h*4+ff, sim patched in
            if (lane < 8) {
                int qidx = own_base + lane;
                v4f v = neg4;
                if (qidx == q_seg) v[r] = sim;
                __builtin_nontemporal_store(v, &orow[(size_t)(h * 4 + ff) * 256 + qidx]);
            }
        }
    }
}

extern "C" void kernel_launch(void* const* d_in, const int* in_sizes, int n_in,
                              void* d_out, int out_size, void* d_ws, size_t ws_size,
                              hipStream_t stream) {
    const float* lhs = (const float*)d_in[0];
    const float* rhs = (const float*)d_in[1];
    float* out = (float*)d_out;

    int grid = 6138;   // 2046 fill blocks + 4092 dot blocks, interleaved 1:2
    lcs_kernel<<<grid, 256, 0, stream>>>(lhs, rhs, out);
}